// Round 6
// baseline (843.524 us; speedup 1.0000x reference)
//
#include <hip/hip_runtime.h>
#include <hip/hip_bf16.h>

#define TT 8192      // tokens
#define DD 1024
#define EE 8
#define HH 4096
#define SLOTS 16384  // TT * K
#define SLOTSP (SLOTS + 256)
#define MAXRT2 (SLOTS / 256 + EE)  // 72 worst-case 256-row tiles

typedef __bf16 bf16x8 __attribute__((ext_vector_type(8)));
typedef float f32x4 __attribute__((ext_vector_type(4)));

__device__ __forceinline__ float bf2f(unsigned u) { return __uint_as_float(u << 16); }
__device__ __forceinline__ unsigned short f2bf(float f) {
  __hip_bfloat16 h = __float2bfloat16(f);
  return __builtin_bit_cast(unsigned short, h);
}
__device__ __forceinline__ f32x4 MF(bf16x8 a, bf16x8 b, f32x4 c) {
  return __builtin_amdgcn_mfma_f32_16x16x32_bf16(a, b, c, 0, 0, 0);
}

// ctrl layout (ints): [0..7]=cnt  [8..16]=off  [25..33]=rtp (256-row tiles)

// -------------------- router: LN stats + logits + top2 + ranks --------------------
__global__ __launch_bounds__(256) void k_router(
    const float* __restrict__ x, const float* __restrict__ rls,
    const float* __restrict__ rlb, const float* __restrict__ rw,
    const float* __restrict__ rb, unsigned short* __restrict__ xhat,
    int* __restrict__ ctrl, int* __restrict__ topk, float* __restrict__ gates,
    int* __restrict__ ranks) {
  const int t = blockIdx.x, tid = threadIdx.x;
  const int lane = tid & 63, wave = tid >> 6;
  float4 v = ((const float4*)(x + (size_t)t * DD))[tid];
  float s = v.x + v.y + v.z + v.w;
  float s2 = v.x * v.x + v.y * v.y + v.z * v.z + v.w * v.w;
#pragma unroll
  for (int o = 32; o > 0; o >>= 1) { s += __shfl_down(s, o); s2 += __shfl_down(s2, o); }
  __shared__ float rs[4], rs2[4];
  if (lane == 0) { rs[wave] = s; rs2[wave] = s2; }
  __syncthreads();
  float ts = rs[0] + rs[1] + rs[2] + rs[3];
  float ts2 = rs2[0] + rs2[1] + rs2[2] + rs2[3];
  float mean = ts * (1.0f / DD);
  float var = ts2 * (1.0f / DD) - mean * mean;
  float inv = rsqrtf(var + 1e-6f);
  float xh0 = (v.x - mean) * inv, xh1 = (v.y - mean) * inv;
  float xh2 = (v.z - mean) * inv, xh3 = (v.w - mean) * inv;
  ushort4 pk;
  pk.x = f2bf(xh0); pk.y = f2bf(xh1); pk.z = f2bf(xh2); pk.w = f2bf(xh3);
  ((ushort4*)(xhat + (size_t)t * DD))[tid] = pk;
  float4 sc = ((const float4*)rls)[tid];
  float4 bi = ((const float4*)rlb)[tid];
  float r0 = fmaf(xh0, sc.x, bi.x), r1 = fmaf(xh1, sc.y, bi.y);
  float r2 = fmaf(xh2, sc.z, bi.z), r3 = fmaf(xh3, sc.w, bi.w);
  float pe[EE];
#pragma unroll
  for (int e = 0; e < EE; ++e) {
    float4 w = ((const float4*)(rw + (size_t)e * DD))[tid];
    pe[e] = fmaf(r0, w.x, fmaf(r1, w.y, fmaf(r2, w.z, r3 * w.w)));
  }
#pragma unroll
  for (int o = 32; o > 0; o >>= 1) {
#pragma unroll
    for (int e = 0; e < EE; ++e) pe[e] += __shfl_down(pe[e], o);
  }
  __shared__ float lred[4][EE];
  if (lane == 0) {
    for (int e = 0; e < EE; ++e) lred[wave][e] = pe[e];
  }
  __syncthreads();
  if (tid == 0) {
    float lg[EE];
    for (int e = 0; e < EE; ++e)
      lg[e] = lred[0][e] + lred[1][e] + lred[2][e] + lred[3][e] + rb[e];
    int i1 = 0;
    for (int e = 1; e < EE; ++e) if (lg[e] > lg[i1]) i1 = e;
    int i2 = -1;
    for (int e = 0; e < EE; ++e) { if (e == i1) continue; if (i2 < 0 || lg[e] > lg[i2]) i2 = e; }
    float eb = expf(lg[i2] - lg[i1]);
    float den = 1.0f / (1.0f + eb);
    topk[t] = i1 | (i2 << 8);
    gates[2 * t] = den;
    gates[2 * t + 1] = eb * den;
    ranks[2 * t] = atomicAdd(&ctrl[i1], 1);
    ranks[2 * t + 1] = atomicAdd(&ctrl[i2], 1);
  }
}

// -------------------- offsets / row-tile prefix (256-row tiles) -------
__global__ void k_offsets(int* __restrict__ ctrl) {
  if (threadIdx.x == 0 && blockIdx.x == 0) {
    int o = 0, r = 0;
    ctrl[8] = 0; ctrl[25] = 0;
    for (int e = 0; e < EE; ++e) {
      int c = ctrl[e];
      o += c;
      ctrl[9 + e] = o;
      r += (c + 255) >> 8;
      ctrl[26 + e] = r;
    }
  }
}

// -------------------- build A rows (expert LN applied to xhat), no atomics ------
__global__ __launch_bounds__(128) void k_build(
    const unsigned short* __restrict__ xhat, const float* __restrict__ els,
    const float* __restrict__ elb, const int* __restrict__ ctrl,
    const int* __restrict__ topk, const int* __restrict__ ranks,
    unsigned short* __restrict__ A, int* __restrict__ tok_pos) {
  int p = blockIdx.x, t = p >> 1, k = p & 1;
  int e = (topk[t] >> (k * 8)) & 0xff;
  int pos = ctrl[8 + e] + ranks[p];
  if (threadIdx.x == 0) tok_pos[p] = pos;
  int i = threadIdx.x * 8;
  uint4 xv = *(const uint4*)(xhat + (size_t)t * DD + i);
  const float* sp = els + (size_t)e * DD + i;
  const float* bp = elb + (size_t)e * DD + i;
  float4 s0 = *(const float4*)sp, s1 = *(const float4*)(sp + 4);
  float4 b0 = *(const float4*)bp, b1 = *(const float4*)(bp + 4);
  unsigned r0 = (unsigned)f2bf(fmaf(bf2f(xv.x & 0xffffu), s0.x, b0.x)) |
                ((unsigned)f2bf(fmaf(bf2f(xv.x >> 16), s0.y, b0.y)) << 16);
  unsigned r1 = (unsigned)f2bf(fmaf(bf2f(xv.y & 0xffffu), s0.z, b0.z)) |
                ((unsigned)f2bf(fmaf(bf2f(xv.y >> 16), s0.w, b0.w)) << 16);
  unsigned r2 = (unsigned)f2bf(fmaf(bf2f(xv.z & 0xffffu), s1.x, b1.x)) |
                ((unsigned)f2bf(fmaf(bf2f(xv.z >> 16), s1.y, b1.y)) << 16);
  unsigned r3 = (unsigned)f2bf(fmaf(bf2f(xv.w & 0xffffu), s1.z, b1.z)) |
                ((unsigned)f2bf(fmaf(bf2f(xv.w >> 16), s1.w, b1.w)) << 16);
  uint4 ov; ov.x = r0; ov.y = r1; ov.z = r2; ov.w = r3;
  *(uint4*)(A + (size_t)pos * DD + i) = ov;
}

// -------------------- weights fp32 -> bf16 --------------------
__global__ __launch_bounds__(256) void k_wconv(
    const float* __restrict__ w1, const float* __restrict__ w2,
    unsigned short* __restrict__ w1b, unsigned short* __restrict__ w2b) {
  size_t i = (size_t)blockIdx.x * 256 + threadIdx.x;
  const size_t n4 = (size_t)EE * HH * DD / 4;
  const float4* src; unsigned short* dst; size_t j;
  if (i < n4) { src = (const float4*)w1; dst = w1b; j = i; }
  else        { src = (const float4*)w2; dst = w2b; j = i - n4; }
  float4 v = src[j];
  ushort4 ov;
  ov.x = f2bf(v.x); ov.y = f2bf(v.y); ov.z = f2bf(v.z); ov.w = f2bf(v.w);
  ((ushort4*)dst)[j] = ov;
}

// ======= grouped GEMM, 256x256, BK=64, 2-phase loop, A-panel-major order =======
// LDS: buf p (p = kt&1) at p*65536: A 256x64 (32KB) at +0, B at +32768.
// st_16x32 swizzle; staged linear via inverse-swizzled per-lane global source.
// Per iter kt: STAGE(buf p^1, kt+1) -> 24 ds_read (buf p) -> lgkmcnt(0) ->
// 64 MFMA -> vmcnt(0) -> ONE s_barrier. (RAW/WAR proofs in R5 notes.)
// BLOCK ORDER (the R6 lever): lin2 (contiguous on one XCD via m204 swizzle)
// maps A-panel-major: by = lin2 % gridY, bx = lin2 / gridY. All gridY blocks
// sharing an A row-panel run consecutively on ONE XCD -> A panel stays in that
// XCD's L2 (512 KB << 4 MB) and is HBM-fetched ~once; B/W streams but is
// L3-resident (67 MB). Previous bx-major order re-fetched A gridY times
// (fc1 FETCH 310 MB vs 100 MB ideal).
#define GLL(S, D)                                                              \
  __builtin_amdgcn_global_load_lds(                                            \
      (const __attribute__((address_space(1))) unsigned int*)(S),              \
      (__attribute__((address_space(3))) unsigned int*)(D), 16, 0, 0)
// wave w stages rows 16w..16w+15 and 128+16w..+15 of both A and B (4 GLL each)
#define STAGE(P, KT) do {                                                      \
    const unsigned short* sA_ = pA + (size_t)(KT) * 64;                        \
    const unsigned short* sB_ = pB + (size_t)(KT) * 64;                        \
    char* dA_ = sL + (P) * 65536;                                              \
    char* dB_ = dA_ + 32768;                                                   \
    GLL(sA_, dA_);                  GLL(sA_ + 32, dA_ + 1024);                 \
    GLL(sA_ + 128 * KDIM, dA_ + 16384); GLL(sA_ + 128 * KDIM + 32, dA_ + 17408); \
    GLL(sB_, dB_);                  GLL(sB_ + 32, dB_ + 1024);                 \
    GLL(sB_ + 128 * KDIM, dB_ + 16384); GLL(sB_ + 128 * KDIM + 32, dB_ + 17408); \
  } while (0)

template <int KDIM, bool GELU>
__global__ __launch_bounds__(512, 2) void k_gemm3(
    const unsigned short* __restrict__ Amat,  // [SLOTSP][KDIM] bf16
    const unsigned short* __restrict__ W,     // [EE][NTOT][KDIM] bf16
    const float* __restrict__ bias,           // [EE][NTOT]
    unsigned short* __restrict__ Outm,        // [SLOTSP][NTOT] bf16
    const int* __restrict__ ctrl, int NTOT) {
  constexpr int NT = KDIM / 64;  // K-tiles
  __shared__ __align__(16) char smem[131072];
  const int* rtp = ctrl + 25;

  // bijective XCD swizzle (m204): lin2 is contiguous within each XCD's chunk
  const int nwg = gridDim.x * gridDim.y;
  const int lin = blockIdx.y * gridDim.x + blockIdx.x;
  const int xcd = lin & 7, loc = lin >> 3;
  const int q = nwg >> 3, rr = nwg & 7;
  const int lin2 = (xcd < rr ? xcd * (q + 1) : rr * (q + 1) + (xcd - rr) * q) + loc;
  // A-panel-major tile order (R6 lever)
  const int by = lin2 % gridDim.y;
  const int bx = lin2 / gridDim.y;
  if (bx >= rtp[EE]) return;
  int e = 0;
  while (bx >= rtp[e + 1]) ++e;
  const int rt = bx - rtp[e];
  const int row0 = ctrl[8 + e] + rt * 256;
  int vrows = ctrl[e] - rt * 256;
  if (vrows > 256) vrows = 256;
  const int n0 = by * 256;

  const int tid = threadIdx.x, lane = tid & 63, w = tid >> 6;
  const int wr = w >> 2, wc = w & 3;  // 2 row-waves x 4 col-waves; wave out 128x64

  // staging lane geometry (inverse swizzle on the global source)
  const int u = (lane * 16) ^ (((lane >> 5) & 1) << 5);
  const int ri = u >> 6;         // in-subtile row 0..15
  const int ci = (u & 63) >> 1;  // in-subtile col elem 0/8/16/24
  const unsigned short* pA = Amat + (size_t)(row0 + 16 * w + ri) * KDIM + ci;
  const unsigned short* pB = W + ((size_t)e * NTOT + n0 + 16 * w + ri) * KDIM + ci;
  char* sL = smem + (2 * w) * 1024 + lane * 16;

  // fragment-read lane term (swizzled)
  const int lt = (((lane & 15) << 6) | ((lane >> 4) << 4)) ^ (((lane >> 3) & 1) << 5);

  f32x4 acc[8][4];
#pragma unroll
  for (int m = 0; m < 8; ++m)
#pragma unroll
    for (int n = 0; n < 4; ++n) acc[m][n] = (f32x4){0.f, 0.f, 0.f, 0.f};

  bf16x8 a[16], b[8];  // a[2m+kh]: rows wr*128+m*16, k-half kh; b[2n+kh]

  // prologue
  STAGE(0, 0);
  asm volatile("s_waitcnt vmcnt(0)" ::: "memory");
  __builtin_amdgcn_s_barrier();

  for (int kt = 0; kt < NT; ++kt) {
    const int p = kt & 1;
    if (kt + 1 < NT) STAGE(p ^ 1, kt + 1);
    const char* ab = smem + p * 65536 + wr * 16384 + lt;          // subtile (wr*8+m)*2+kh
    const char* bb = smem + p * 65536 + 32768 + wc * 8192 + lt;   // subtile (wc*4+n)*2+kh
#pragma unroll
    for (int m = 0; m < 8; ++m) {
      a[2 * m]     = *(const bf16x8*)(ab + m * 2048);
      a[2 * m + 1] = *(const bf16x8*)(ab + m * 2048 + 1024);
    }
#pragma unroll
    for (int n = 0; n < 4; ++n) {
      b[2 * n]     = *(const bf16x8*)(bb + n * 2048);
      b[2 * n + 1] = *(const bf16x8*)(bb + n * 2048 + 1024);
    }
    asm volatile("s_waitcnt lgkmcnt(0)" ::: "memory");
    __builtin_amdgcn_sched_barrier(0);
    __builtin_amdgcn_s_setprio(1);
#pragma unroll
    for (int kh = 0; kh < 2; ++kh)
#pragma unroll
      for (int m = 0; m < 8; ++m)
#pragma unroll
        for (int n = 0; n < 4; ++n)
          acc[m][n] = MF(a[2 * m + kh], b[2 * n + kh], acc[m][n]);
    __builtin_amdgcn_s_setprio(0);
    asm volatile("s_waitcnt vmcnt(0)" ::: "memory");
    __builtin_amdgcn_s_barrier();
  }

  // epilogue: wave piece rows wr*128+m*16, cols wc*64+n*16
#pragma unroll
  for (int m = 0; m < 8; ++m) {
    const int rbase = wr * 128 + m * 16 + (lane >> 4) * 4;
#pragma unroll
    for (int n = 0; n < 4; ++n) {
      const int col = n0 + wc * 64 + n * 16 + (lane & 15);
      const float bv_ = bias[(size_t)e * NTOT + col];
#pragma unroll
      for (int j = 0; j < 4; ++j) {
        const int r = rbase + j;
        if (r < vrows) {
          float vv = acc[m][n][j] + bv_;
          if constexpr (GELU) vv = 0.5f * vv * (1.0f + erff(vv * 0.70710678f));
          Outm[(size_t)(row0 + r) * NTOT + col] = f2bf(vv);
        }
      }
    }
  }
}

// -------------------- combine: out[t] = g0*Y[p0] + g1*Y[p1] --------------------
__global__ __launch_bounds__(256) void k_combine(
    const unsigned short* __restrict__ Y, const int* __restrict__ tok_pos,
    const float* __restrict__ gates, float* __restrict__ out) {
  int t = blockIdx.x, tid = threadIdx.x;
  int p0 = tok_pos[2 * t], p1 = tok_pos[2 * t + 1];
  float g0 = gates[2 * t], g1 = gates[2 * t + 1];
  ushort4 y0 = ((const ushort4*)(Y + (size_t)p0 * DD))[tid];
  ushort4 y1 = ((const ushort4*)(Y + (size_t)p1 * DD))[tid];
  float4 o;
  o.x = g0 * bf2f(y0.x) + g1 * bf2f(y1.x);
  o.y = g0 * bf2f(y0.y) + g1 * bf2f(y1.y);
  o.z = g0 * bf2f(y0.z) + g1 * bf2f(y1.z);
  o.w = g0 * bf2f(y0.w) + g1 * bf2f(y1.w);
  ((float4*)(out + (size_t)t * DD))[tid] = o;
}

__global__ __launch_bounds__(256) void k_sentinel(float* out, int n) {
  int i = blockIdx.x * 256 + threadIdx.x;
  if (i < n) out[i] = 12345.0f;
}

extern "C" void kernel_launch(void* const* d_in, const int* in_sizes, int n_in,
                              void* d_out, int out_size, void* d_ws, size_t ws_size,
                              hipStream_t stream) {
  const float* x   = (const float*)d_in[0];
  const float* rls = (const float*)d_in[1];
  const float* rlb = (const float*)d_in[2];
  const float* rw  = (const float*)d_in[3];
  const float* rb  = (const float*)d_in[4];
  const float* els = (const float*)d_in[5];
  const float* elb = (const float*)d_in[6];
  const float* w1  = (const float*)d_in[7];
  const float* b1  = (const float*)d_in[8];
  const float* w2  = (const float*)d_in[9];
  const float* b2  = (const float*)d_in[10];
  float* out = (float*)d_out;

  char* wsb = (char*)d_ws;
  size_t o = 0;
  int* ctrl = (int*)(wsb + o);                    o += 256;
  int* tok_pos = (int*)(wsb + o);                 o += (size_t)SLOTS * 4;
  float* gates = (float*)(wsb + o);               o += (size_t)SLOTS * 4;
  int* topk = (int*)(wsb + o);                    o += (size_t)TT * 4;
  int* ranks = (int*)(wsb + o);                   o += (size_t)SLOTS * 4;
  unsigned short* xhat = (unsigned short*)(wsb + o); o += (size_t)TT * DD * 2;
  unsigned short* Abuf = (unsigned short*)(wsb + o); o += (size_t)SLOTSP * DD * 2;
  unsigned short* w1b = (unsigned short*)(wsb + o);  o += (size_t)EE * HH * DD * 2;
  unsigned short* w2b = (unsigned short*)(wsb + o);  o += (size_t)EE * DD * HH * 2;
  unsigned short* Hm = (unsigned short*)(wsb + o);   o += (size_t)SLOTSP * HH * 2;
  unsigned short* Yb = (unsigned short*)(wsb + o);   o += (size_t)SLOTS * DD * 2;

  if (ws_size < o) {
    k_sentinel<<<(out_size + 255) / 256, 256, 0, stream>>>(out, out_size);
    return;
  }

  hipMemsetAsync(ctrl, 0, 256, stream);
  k_router<<<TT, 256, 0, stream>>>(x, rls, rlb, rw, rb, xhat, ctrl, topk, gates, ranks);
  k_wconv<<<65536, 256, 0, stream>>>(w1, w2, w1b, w2b);
  k_offsets<<<1, 64, 0, stream>>>(ctrl);
  k_build<<<SLOTS, 128, 0, stream>>>(xhat, els, elb, ctrl, topk, ranks, Abuf, tok_pos);
  k_gemm3<DD, true><<<dim3(MAXRT2, HH / 256), 512, 0, stream>>>(Abuf, w1b, b1, Hm, ctrl, HH);
  k_gemm3<HH, false><<<dim3(MAXRT2, DD / 256), 512, 0, stream>>>(Hm, w2b, b2, Yb, ctrl, DD);
  k_combine<<<TT, 256, 0, stream>>>(Yb, tok_pos, gates, out);
}

// Round 7
// 760.562 us; speedup vs baseline: 1.1091x; 1.1091x over previous
//
#include <hip/hip_runtime.h>
#include <hip/hip_bf16.h>

#define TT 8192      // tokens
#define DD 1024
#define EE 8
#define HH 4096
#define SLOTS 16384  // TT * K
#define SLOTSP (SLOTS + 256)
#define MAXRT1 (SLOTS / 128 + EE)  // 136 worst-case 128-row tiles

typedef __bf16 bf16x8 __attribute__((ext_vector_type(8)));
typedef float f32x4 __attribute__((ext_vector_type(4)));

__device__ __forceinline__ float bf2f(unsigned u) { return __uint_as_float(u << 16); }
__device__ __forceinline__ unsigned short f2bf(float f) {
  __hip_bfloat16 h = __float2bfloat16(f);
  return __builtin_bit_cast(unsigned short, h);
}
__device__ __forceinline__ f32x4 MF(bf16x8 a, bf16x8 b, f32x4 c) {
  return __builtin_amdgcn_mfma_f32_16x16x32_bf16(a, b, c, 0, 0, 0);
}

// ctrl layout (ints): [0..7]=cnt  [8..16]=off  [25..33]=rtp (128-row tiles)

// -------------------- router: LN stats + logits + top2 + ranks --------------------
__global__ __launch_bounds__(256) void k_router(
    const float* __restrict__ x, const float* __restrict__ rls,
    const float* __restrict__ rlb, const float* __restrict__ rw,
    const float* __restrict__ rb, unsigned short* __restrict__ xhat,
    int* __restrict__ ctrl, int* __restrict__ topk, float* __restrict__ gates,
    int* __restrict__ ranks) {
  const int t = blockIdx.x, tid = threadIdx.x;
  const int lane = tid & 63, wave = tid >> 6;
  float4 v = ((const float4*)(x + (size_t)t * DD))[tid];
  float s = v.x + v.y + v.z + v.w;
  float s2 = v.x * v.x + v.y * v.y + v.z * v.z + v.w * v.w;
#pragma unroll
  for (int o = 32; o > 0; o >>= 1) { s += __shfl_down(s, o); s2 += __shfl_down(s2, o); }
  __shared__ float rs[4], rs2[4];
  if (lane == 0) { rs[wave] = s; rs2[wave] = s2; }
  __syncthreads();
  float ts = rs[0] + rs[1] + rs[2] + rs[3];
  float ts2 = rs2[0] + rs2[1] + rs2[2] + rs2[3];
  float mean = ts * (1.0f / DD);
  float var = ts2 * (1.0f / DD) - mean * mean;
  float inv = rsqrtf(var + 1e-6f);
  float xh0 = (v.x - mean) * inv, xh1 = (v.y - mean) * inv;
  float xh2 = (v.z - mean) * inv, xh3 = (v.w - mean) * inv;
  ushort4 pk;
  pk.x = f2bf(xh0); pk.y = f2bf(xh1); pk.z = f2bf(xh2); pk.w = f2bf(xh3);
  ((ushort4*)(xhat + (size_t)t * DD))[tid] = pk;
  float4 sc = ((const float4*)rls)[tid];
  float4 bi = ((const float4*)rlb)[tid];
  float r0 = fmaf(xh0, sc.x, bi.x), r1 = fmaf(xh1, sc.y, bi.y);
  float r2 = fmaf(xh2, sc.z, bi.z), r3 = fmaf(xh3, sc.w, bi.w);
  float pe[EE];
#pragma unroll
  for (int e = 0; e < EE; ++e) {
    float4 w = ((const float4*)(rw + (size_t)e * DD))[tid];
    pe[e] = fmaf(r0, w.x, fmaf(r1, w.y, fmaf(r2, w.z, r3 * w.w)));
  }
#pragma unroll
  for (int o = 32; o > 0; o >>= 1) {
#pragma unroll
    for (int e = 0; e < EE; ++e) pe[e] += __shfl_down(pe[e], o);
  }
  __shared__ float lred[4][EE];
  if (lane == 0) {
    for (int e = 0; e < EE; ++e) lred[wave][e] = pe[e];
  }
  __syncthreads();
  if (tid == 0) {
    float lg[EE];
    for (int e = 0; e < EE; ++e)
      lg[e] = lred[0][e] + lred[1][e] + lred[2][e] + lred[3][e] + rb[e];
    int i1 = 0;
    for (int e = 1; e < EE; ++e) if (lg[e] > lg[i1]) i1 = e;
    int i2 = -1;
    for (int e = 0; e < EE; ++e) { if (e == i1) continue; if (i2 < 0 || lg[e] > lg[i2]) i2 = e; }
    float eb = expf(lg[i2] - lg[i1]);
    float den = 1.0f / (1.0f + eb);
    topk[t] = i1 | (i2 << 8);
    gates[2 * t] = den;
    gates[2 * t + 1] = eb * den;
    ranks[2 * t] = atomicAdd(&ctrl[i1], 1);
    ranks[2 * t + 1] = atomicAdd(&ctrl[i2], 1);
  }
}

// -------------------- offsets / row-tile prefix (128-row tiles) -------
__global__ void k_offsets(int* __restrict__ ctrl) {
  if (threadIdx.x == 0 && blockIdx.x == 0) {
    int o = 0, r = 0;
    ctrl[8] = 0; ctrl[25] = 0;
    for (int e = 0; e < EE; ++e) {
      int c = ctrl[e];
      o += c;
      ctrl[9 + e] = o;
      r += (c + 127) >> 7;
      ctrl[26 + e] = r;
    }
  }
}

// -------------------- build A rows (expert LN applied to xhat), no atomics ------
__global__ __launch_bounds__(128) void k_build(
    const unsigned short* __restrict__ xhat, const float* __restrict__ els,
    const float* __restrict__ elb, const int* __restrict__ ctrl,
    const int* __restrict__ topk, const int* __restrict__ ranks,
    unsigned short* __restrict__ A, int* __restrict__ tok_pos) {
  int p = blockIdx.x, t = p >> 1, k = p & 1;
  int e = (topk[t] >> (k * 8)) & 0xff;
  int pos = ctrl[8 + e] + ranks[p];
  if (threadIdx.x == 0) tok_pos[p] = pos;
  int i = threadIdx.x * 8;
  uint4 xv = *(const uint4*)(xhat + (size_t)t * DD + i);
  const float* sp = els + (size_t)e * DD + i;
  const float* bp = elb + (size_t)e * DD + i;
  float4 s0 = *(const float4*)sp, s1 = *(const float4*)(sp + 4);
  float4 b0 = *(const float4*)bp, b1 = *(const float4*)(bp + 4);
  unsigned r0 = (unsigned)f2bf(fmaf(bf2f(xv.x & 0xffffu), s0.x, b0.x)) |
                ((unsigned)f2bf(fmaf(bf2f(xv.x >> 16), s0.y, b0.y)) << 16);
  unsigned r1 = (unsigned)f2bf(fmaf(bf2f(xv.y & 0xffffu), s0.z, b0.z)) |
                ((unsigned)f2bf(fmaf(bf2f(xv.y >> 16), s0.w, b0.w)) << 16);
  unsigned r2 = (unsigned)f2bf(fmaf(bf2f(xv.z & 0xffffu), s1.x, b1.x)) |
                ((unsigned)f2bf(fmaf(bf2f(xv.z >> 16), s1.y, b1.y)) << 16);
  unsigned r3 = (unsigned)f2bf(fmaf(bf2f(xv.w & 0xffffu), s1.z, b1.z)) |
                ((unsigned)f2bf(fmaf(bf2f(xv.w >> 16), s1.w, b1.w)) << 16);
  uint4 ov; ov.x = r0; ov.y = r1; ov.z = r2; ov.w = r3;
  *(uint4*)(A + (size_t)pos * DD + i) = ov;
}

// -------------------- weights fp32 -> bf16 --------------------
__global__ __launch_bounds__(256) void k_wconv(
    const float* __restrict__ w1, const float* __restrict__ w2,
    unsigned short* __restrict__ w1b, unsigned short* __restrict__ w2b) {
  size_t i = (size_t)blockIdx.x * 256 + threadIdx.x;
  const size_t n4 = (size_t)EE * HH * DD / 4;
  const float4* src; unsigned short* dst; size_t j;
  if (i < n4) { src = (const float4*)w1; dst = w1b; j = i; }
  else        { src = (const float4*)w2; dst = w2b; j = i - n4; }
  float4 v = src[j];
  ushort4 ov;
  ov.x = f2bf(v.x); ov.y = f2bf(v.y); ov.z = f2bf(v.z); ov.w = f2bf(v.w);
  ((ushort4*)dst)[j] = ov;
}

// ==== grouped GEMM, 128x128 tile, BK=32, 2-phase, ~3 blocks/CU (m97 geometry) ====
// 256 thr / 4 waves; wave w: wr=w>>1, wc=w&1; per-wave out 64x64 (acc[4][4]).
// LDS: buf p at p*16384: A 128x32 (8KB) + B (8KB). Subtile 16r x 32c = 1KB;
// st_16x32 swizzle (in-subtile byte ^= ((byte>>9)&1)<<5), staged linear via
// inverse-swizzled per-lane global source (both-sides involution, rule #21).
// Per iter kt: STAGE(p^1, kt+1) [4 gll] -> 8 ds_read (buf p) -> lgkmcnt(0) ->
// 16 MFMA -> vmcnt(0) -> ONE barrier. Cross-block overlap at ~3 blocks/CU
// hides the drain (m114 mechanism) — this was the missing occupancy in R2-R6.
// Block order: bijective XCD swizzle + A-panel-major (by=lin2%gridY) so one
// XCD's consecutive blocks reuse one 256KB A-panel from its L2 (R6 win).
#define GLL(S, D)                                                              \
  __builtin_amdgcn_global_load_lds(                                            \
      (const __attribute__((address_space(1))) unsigned int*)(S),              \
      (__attribute__((address_space(3))) unsigned int*)(D), 16, 0, 0)
// wave w stages A subtiles 2w,2w+1 (rows 32w+ri, 32w+16+ri) and B same (4 GLL)
#define STAGE(P, KT) do {                                                      \
    const unsigned short* sA_ = pA + (size_t)(KT) * 32;                        \
    const unsigned short* sB_ = pB + (size_t)(KT) * 32;                        \
    char* dA_ = sL + (P) * 16384;                                              \
    char* dB_ = dA_ + 8192;                                                    \
    GLL(sA_, dA_); GLL(sA_ + 16 * KDIM, dA_ + 1024);                           \
    GLL(sB_, dB_); GLL(sB_ + 16 * KDIM, dB_ + 1024);                           \
  } while (0)

template <int KDIM, bool GELU>
__global__ __launch_bounds__(256, 3) void k_gemm4(
    const unsigned short* __restrict__ Amat,  // [SLOTSP][KDIM] bf16
    const unsigned short* __restrict__ W,     // [EE][NTOT][KDIM] bf16
    const float* __restrict__ bias,           // [EE][NTOT]
    unsigned short* __restrict__ Outm,        // [SLOTSP][NTOT] bf16
    const int* __restrict__ ctrl, int NTOT) {
  constexpr int NT = KDIM / 32;  // K-tiles
  __shared__ __align__(16) char smem[32768];
  const int* rtp = ctrl + 25;

  // bijective XCD swizzle (m204): lin2 contiguous within an XCD's chunk
  const int nwg = gridDim.x * gridDim.y;
  const int lin = blockIdx.y * gridDim.x + blockIdx.x;
  const int xcd = lin & 7, loc = lin >> 3;
  const int q = nwg >> 3, rr = nwg & 7;
  const int lin2 = (xcd < rr ? xcd * (q + 1) : rr * (q + 1) + (xcd - rr) * q) + loc;
  // A-panel-major tile order (R6 lever)
  const int by = lin2 % gridDim.y;
  const int bx = lin2 / gridDim.y;
  if (bx >= rtp[EE]) return;
  int e = 0;
  while (bx >= rtp[e + 1]) ++e;
  const int rt = bx - rtp[e];
  const int row0 = ctrl[8 + e] + rt * 128;
  int vrows = ctrl[e] - rt * 128;
  if (vrows > 128) vrows = 128;
  const int n0 = by * 128;

  const int tid = threadIdx.x, lane = tid & 63, w = tid >> 6;
  const int wr = w >> 1, wc = w & 1;  // 2x2 waves; per-wave out 64x64

  // staging lane geometry (inverse swizzle on the global source)
  const int u = (lane * 16) ^ (((lane >> 5) & 1) << 5);
  const int ri = u >> 6;         // in-subtile row 0..15
  const int ci = (u & 63) >> 1;  // in-subtile col elem 0/8/16/24
  const unsigned short* pA = Amat + (size_t)(row0 + 32 * w + ri) * KDIM + ci;
  const unsigned short* pB = W + ((size_t)e * NTOT + n0 + 32 * w + ri) * KDIM + ci;
  char* sL = smem + (2 * w) * 1024 + lane * 16;

  // fragment-read lane term (swizzled): row=lane&15, col byte=(lane>>4)*16
  const int lt = (((lane & 15) << 6) | ((lane >> 4) << 4)) ^ (((lane >> 3) & 1) << 5);

  f32x4 acc[4][4];
#pragma unroll
  for (int m = 0; m < 4; ++m)
#pragma unroll
    for (int n = 0; n < 4; ++n) acc[m][n] = (f32x4){0.f, 0.f, 0.f, 0.f};

  bf16x8 a[4], b[4];

  // prologue
  STAGE(0, 0);
  asm volatile("s_waitcnt vmcnt(0)" ::: "memory");
  __builtin_amdgcn_s_barrier();

  for (int kt = 0; kt < NT; ++kt) {
    const int p = kt & 1;
    if (kt + 1 < NT) STAGE(p ^ 1, kt + 1);
    const char* ab = smem + p * 16384 + wr * 4096 + lt;         // subtile wr*4+m
    const char* bb = smem + p * 16384 + 8192 + wc * 4096 + lt;  // subtile wc*4+n
#pragma unroll
    for (int m = 0; m < 4; ++m) a[m] = *(const bf16x8*)(ab + m * 1024);
#pragma unroll
    for (int n = 0; n < 4; ++n) b[n] = *(const bf16x8*)(bb + n * 1024);
    asm volatile("s_waitcnt lgkmcnt(0)" ::: "memory");
    __builtin_amdgcn_sched_barrier(0);
    __builtin_amdgcn_s_setprio(1);
#pragma unroll
    for (int m = 0; m < 4; ++m)
#pragma unroll
      for (int n = 0; n < 4; ++n)
        acc[m][n] = MF(a[m], b[n], acc[m][n]);
    __builtin_amdgcn_s_setprio(0);
    asm volatile("s_waitcnt vmcnt(0)" ::: "memory");
    __builtin_amdgcn_s_barrier();
  }

  // epilogue: wave piece rows wr*64+m*16, cols wc*64+n*16
#pragma unroll
  for (int m = 0; m < 4; ++m) {
    const int rbase = wr * 64 + m * 16 + (lane >> 4) * 4;
#pragma unroll
    for (int n = 0; n < 4; ++n) {
      const int col = n0 + wc * 64 + n * 16 + (lane & 15);
      const float bv_ = bias[(size_t)e * NTOT + col];
#pragma unroll
      for (int j = 0; j < 4; ++j) {
        const int r = rbase + j;
        if (r < vrows) {
          float vv = acc[m][n][j] + bv_;
          if constexpr (GELU) vv = 0.5f * vv * (1.0f + erff(vv * 0.70710678f));
          Outm[(size_t)(row0 + r) * NTOT + col] = f2bf(vv);
        }
      }
    }
  }
}

// -------------------- combine: out[t] = g0*Y[p0] + g1*Y[p1] --------------------
__global__ __launch_bounds__(256) void k_combine(
    const unsigned short* __restrict__ Y, const int* __restrict__ tok_pos,
    const float* __restrict__ gates, float* __restrict__ out) {
  int t = blockIdx.x, tid = threadIdx.x;
  int p0 = tok_pos[2 * t], p1 = tok_pos[2 * t + 1];
  float g0 = gates[2 * t], g1 = gates[2 * t + 1];
  ushort4 y0 = ((const ushort4*)(Y + (size_t)p0 * DD))[tid];
  ushort4 y1 = ((const ushort4*)(Y + (size_t)p1 * DD))[tid];
  float4 o;
  o.x = g0 * bf2f(y0.x) + g1 * bf2f(y1.x);
  o.y = g0 * bf2f(y0.y) + g1 * bf2f(y1.y);
  o.z = g0 * bf2f(y0.z) + g1 * bf2f(y1.z);
  o.w = g0 * bf2f(y0.w) + g1 * bf2f(y1.w);
  ((float4*)(out + (size_t)t * DD))[tid] = o;
}

__global__ __launch_bounds__(256) void k_sentinel(float* out, int n) {
  int i = blockIdx.x * 256 + threadIdx.x;
  if (i < n) out[i] = 12345.0f;
}

extern "C" void kernel_launch(void* const* d_in, const int* in_sizes, int n_in,
                              void* d_out, int out_size, void* d_ws, size_t ws_size,
                              hipStream_t stream) {
  const float* x   = (const float*)d_in[0];
  const float* rls = (const float*)d_in[1];
  const float* rlb = (const float*)d_in[2];
  const float* rw  = (const float*)d_in[3];
  const float* rb  = (const float*)d_in[4];
  const float* els = (const float*)d_in[5];
  const float* elb = (const float*)d_in[6];
  const float* w1  = (const float*)d_in[7];
  const float* b1  = (const float*)d_in[8];
  const float* w2  = (const float*)d_in[9];
  const float* b2  = (const float*)d_in[10];
  float* out = (float*)d_out;

  char* wsb = (char*)d_ws;
  size_t o = 0;
  int* ctrl = (int*)(wsb + o);                    o += 256;
  int* tok_pos = (int*)(wsb + o);                 o += (size_t)SLOTS * 4;
  float* gates = (float*)(wsb + o);               o += (size_t)SLOTS * 4;
  int* topk = (int*)(wsb + o);                    o += (size_t)TT * 4;
  int* ranks = (int*)(wsb + o);                   o += (size_t)SLOTS * 4;
  unsigned short* xhat = (unsigned short*)(wsb + o); o += (size_t)TT * DD * 2;
  unsigned short* Abuf = (unsigned short*)(wsb + o); o += (size_t)SLOTSP * DD * 2;
  unsigned short* w1b = (unsigned short*)(wsb + o);  o += (size_t)EE * HH * DD * 2;
  unsigned short* w2b = (unsigned short*)(wsb + o);  o += (size_t)EE * DD * HH * 2;
  unsigned short* Hm = (unsigned short*)(wsb + o);   o += (size_t)SLOTSP * HH * 2;
  unsigned short* Yb = (unsigned short*)(wsb + o);   o += (size_t)SLOTS * DD * 2;

  if (ws_size < o) {
    k_sentinel<<<(out_size + 255) / 256, 256, 0, stream>>>(out, out_size);
    return;
  }

  hipMemsetAsync(ctrl, 0, 256, stream);
  k_router<<<TT, 256, 0, stream>>>(x, rls, rlb, rw, rb, xhat, ctrl, topk, gates, ranks);
  k_wconv<<<65536, 256, 0, stream>>>(w1, w2, w1b, w2b);
  k_offsets<<<1, 64, 0, stream>>>(ctrl);
  k_build<<<SLOTS, 128, 0, stream>>>(xhat, els, elb, ctrl, topk, ranks, Abuf, tok_pos);
  k_gemm4<DD, true><<<dim3(MAXRT1, HH / 128), 256, 0, stream>>>(Abuf, w1b, b1, Hm, ctrl, HH);
  k_gemm4<HH, false><<<dim3(MAXRT1, DD / 128), 256, 0, stream>>>(Hm, w2b, b2, Yb, ctrl, DD);
  k_combine<<<TT, 256, 0, stream>>>(Yb, tok_pos, gates, out);
}

// Round 8
// 745.084 us; speedup vs baseline: 1.1321x; 1.0208x over previous
//
#include <hip/hip_runtime.h>
#include <hip/hip_bf16.h>

#define TT 8192      // tokens
#define DD 1024
#define EE 8
#define HH 4096
#define SLOTS 16384  // TT * K
#define SLOTSP (SLOTS + 256)
#define MAXRT1 (SLOTS / 128 + EE)  // 136 worst-case 128-row tiles

typedef __bf16 bf16x8 __attribute__((ext_vector_type(8)));
typedef float f32x4 __attribute__((ext_vector_type(4)));

__device__ __forceinline__ float bf2f(unsigned u) { return __uint_as_float(u << 16); }
__device__ __forceinline__ unsigned short f2bf(float f) {
  __hip_bfloat16 h = __float2bfloat16(f);
  return __builtin_bit_cast(unsigned short, h);
}
__device__ __forceinline__ f32x4 MF(bf16x8 a, bf16x8 b, f32x4 c) {
  return __builtin_amdgcn_mfma_f32_16x16x32_bf16(a, b, c, 0, 0, 0);
}

// ctrl layout (ints): [0..7]=cnt  [8..16]=off  [25..33]=rtp (128-row tiles)

// -------------------- router: LN stats + logits + top2 + ranks --------------------
__global__ __launch_bounds__(256) void k_router(
    const float* __restrict__ x, const float* __restrict__ rls,
    const float* __restrict__ rlb, const float* __restrict__ rw,
    const float* __restrict__ rb, unsigned short* __restrict__ xhat,
    int* __restrict__ ctrl, int* __restrict__ topk, float* __restrict__ gates,
    int* __restrict__ ranks) {
  const int t = blockIdx.x, tid = threadIdx.x;
  const int lane = tid & 63, wave = tid >> 6;
  float4 v = ((const float4*)(x + (size_t)t * DD))[tid];
  float s = v.x + v.y + v.z + v.w;
  float s2 = v.x * v.x + v.y * v.y + v.z * v.z + v.w * v.w;
#pragma unroll
  for (int o = 32; o > 0; o >>= 1) { s += __shfl_down(s, o); s2 += __shfl_down(s2, o); }
  __shared__ float rs[4], rs2[4];
  if (lane == 0) { rs[wave] = s; rs2[wave] = s2; }
  __syncthreads();
  float ts = rs[0] + rs[1] + rs[2] + rs[3];
  float ts2 = rs2[0] + rs2[1] + rs2[2] + rs2[3];
  float mean = ts * (1.0f / DD);
  float var = ts2 * (1.0f / DD) - mean * mean;
  float inv = rsqrtf(var + 1e-6f);
  float xh0 = (v.x - mean) * inv, xh1 = (v.y - mean) * inv;
  float xh2 = (v.z - mean) * inv, xh3 = (v.w - mean) * inv;
  ushort4 pk;
  pk.x = f2bf(xh0); pk.y = f2bf(xh1); pk.z = f2bf(xh2); pk.w = f2bf(xh3);
  ((ushort4*)(xhat + (size_t)t * DD))[tid] = pk;
  float4 sc = ((const float4*)rls)[tid];
  float4 bi = ((const float4*)rlb)[tid];
  float r0 = fmaf(xh0, sc.x, bi.x), r1 = fmaf(xh1, sc.y, bi.y);
  float r2 = fmaf(xh2, sc.z, bi.z), r3 = fmaf(xh3, sc.w, bi.w);
  float pe[EE];
#pragma unroll
  for (int e = 0; e < EE; ++e) {
    float4 w = ((const float4*)(rw + (size_t)e * DD))[tid];
    pe[e] = fmaf(r0, w.x, fmaf(r1, w.y, fmaf(r2, w.z, r3 * w.w)));
  }
#pragma unroll
  for (int o = 32; o > 0; o >>= 1) {
#pragma unroll
    for (int e = 0; e < EE; ++e) pe[e] += __shfl_down(pe[e], o);
  }
  __shared__ float lred[4][EE];
  if (lane == 0) {
    for (int e = 0; e < EE; ++e) lred[wave][e] = pe[e];
  }
  __syncthreads();
  if (tid == 0) {
    float lg[EE];
    for (int e = 0; e < EE; ++e)
      lg[e] = lred[0][e] + lred[1][e] + lred[2][e] + lred[3][e] + rb[e];
    int i1 = 0;
    for (int e = 1; e < EE; ++e) if (lg[e] > lg[i1]) i1 = e;
    int i2 = -1;
    for (int e = 0; e < EE; ++e) { if (e == i1) continue; if (i2 < 0 || lg[e] > lg[i2]) i2 = e; }
    float eb = expf(lg[i2] - lg[i1]);
    float den = 1.0f / (1.0f + eb);
    topk[t] = i1 | (i2 << 8);
    gates[2 * t] = den;
    gates[2 * t + 1] = eb * den;
    ranks[2 * t] = atomicAdd(&ctrl[i1], 1);
    ranks[2 * t + 1] = atomicAdd(&ctrl[i2], 1);
  }
}

// -------------------- offsets / row-tile prefix (128-row tiles) -------
__global__ void k_offsets(int* __restrict__ ctrl) {
  if (threadIdx.x == 0 && blockIdx.x == 0) {
    int o = 0, r = 0;
    ctrl[8] = 0; ctrl[25] = 0;
    for (int e = 0; e < EE; ++e) {
      int c = ctrl[e];
      o += c;
      ctrl[9 + e] = o;
      r += (c + 127) >> 7;
      ctrl[26 + e] = r;
    }
  }
}

// -------------------- build A rows (expert LN applied to xhat), no atomics ------
__global__ __launch_bounds__(128) void k_build(
    const unsigned short* __restrict__ xhat, const float* __restrict__ els,
    const float* __restrict__ elb, const int* __restrict__ ctrl,
    const int* __restrict__ topk, const int* __restrict__ ranks,
    unsigned short* __restrict__ A, int* __restrict__ tok_pos) {
  int p = blockIdx.x, t = p >> 1, k = p & 1;
  int e = (topk[t] >> (k * 8)) & 0xff;
  int pos = ctrl[8 + e] + ranks[p];
  if (threadIdx.x == 0) tok_pos[p] = pos;
  int i = threadIdx.x * 8;
  uint4 xv = *(const uint4*)(xhat + (size_t)t * DD + i);
  const float* sp = els + (size_t)e * DD + i;
  const float* bp = elb + (size_t)e * DD + i;
  float4 s0 = *(const float4*)sp, s1 = *(const float4*)(sp + 4);
  float4 b0 = *(const float4*)bp, b1 = *(const float4*)(bp + 4);
  unsigned r0 = (unsigned)f2bf(fmaf(bf2f(xv.x & 0xffffu), s0.x, b0.x)) |
                ((unsigned)f2bf(fmaf(bf2f(xv.x >> 16), s0.y, b0.y)) << 16);
  unsigned r1 = (unsigned)f2bf(fmaf(bf2f(xv.y & 0xffffu), s0.z, b0.z)) |
                ((unsigned)f2bf(fmaf(bf2f(xv.y >> 16), s0.w, b0.w)) << 16);
  unsigned r2 = (unsigned)f2bf(fmaf(bf2f(xv.z & 0xffffu), s1.x, b1.x)) |
                ((unsigned)f2bf(fmaf(bf2f(xv.z >> 16), s1.y, b1.y)) << 16);
  unsigned r3 = (unsigned)f2bf(fmaf(bf2f(xv.w & 0xffffu), s1.z, b1.z)) |
                ((unsigned)f2bf(fmaf(bf2f(xv.w >> 16), s1.w, b1.w)) << 16);
  uint4 ov; ov.x = r0; ov.y = r1; ov.z = r2; ov.w = r3;
  *(uint4*)(A + (size_t)pos * DD + i) = ov;
}

// -------------------- weights fp32 -> bf16 --------------------
__global__ __launch_bounds__(256) void k_wconv(
    const float* __restrict__ w1, const float* __restrict__ w2,
    unsigned short* __restrict__ w1b, unsigned short* __restrict__ w2b) {
  size_t i = (size_t)blockIdx.x * 256 + threadIdx.x;
  const size_t n4 = (size_t)EE * HH * DD / 4;
  const float4* src; unsigned short* dst; size_t j;
  if (i < n4) { src = (const float4*)w1; dst = w1b; j = i; }
  else        { src = (const float4*)w2; dst = w2b; j = i - n4; }
  float4 v = src[j];
  ushort4 ov;
  ov.x = f2bf(v.x); ov.y = f2bf(v.y); ov.z = f2bf(v.z); ov.w = f2bf(v.w);
  ((ushort4*)dst)[j] = ov;
}

// ==== grouped GEMM, 128x128, BK=32, 3 blocks/CU, UNPINNED m97-style loop ====
// 256 thr / 4 waves; wave w: wr=w>>1, wc=w&1; per-wave out 64x64 (acc[4][4]).
// LDS: buf p at p*16384: A 128x32 (8KB) + B (8KB). Subtile 16r x 32c = 1KB;
// st_16x32 swizzle (in-subtile byte ^= ((byte>>9)&1)<<5), staged linear via
// inverse-swizzled per-lane global source (both-sides involution, rule #21).
// Loop (R8 lever — no inline-asm waits, no sched_barrier, no setprio; the
// compiler emits fine-grained lgkmcnt(N) so MFMAs start as each frag lands,
// m97/m141 lesson): STAGE(p^1) -> ds_read(p) -> MFMA(p) -> __syncthreads().
// The implicit vmcnt(0)+lgkmcnt(0) drain at __syncthreads covers RAW (staged
// buf landed, all waves) and WAR (reads of buf p retired before next-iter
// overwrite). Block order: bijective XCD swizzle + A-panel-major (R6 win).
#define GLL(S, D)                                                              \
  __builtin_amdgcn_global_load_lds(                                            \
      (const __attribute__((address_space(1))) unsigned int*)(S),              \
      (__attribute__((address_space(3))) unsigned int*)(D), 16, 0, 0)
// wave w stages A subtiles 2w,2w+1 (rows 32w+ri, 32w+16+ri) and B same (4 GLL)
#define STAGE(P, KT) do {                                                      \
    const unsigned short* sA_ = pA + (size_t)(KT) * 32;                        \
    const unsigned short* sB_ = pB + (size_t)(KT) * 32;                        \
    char* dA_ = sL + (P) * 16384;                                              \
    char* dB_ = dA_ + 8192;                                                    \
    GLL(sA_, dA_); GLL(sA_ + 16 * KDIM, dA_ + 1024);                           \
    GLL(sB_, dB_); GLL(sB_ + 16 * KDIM, dB_ + 1024);                           \
  } while (0)

template <int KDIM, bool GELU>
__global__ __launch_bounds__(256, 3) void k_gemm4(
    const unsigned short* __restrict__ Amat,  // [SLOTSP][KDIM] bf16
    const unsigned short* __restrict__ W,     // [EE][NTOT][KDIM] bf16
    const float* __restrict__ bias,           // [EE][NTOT]
    unsigned short* __restrict__ Outm,        // [SLOTSP][NTOT] bf16
    const int* __restrict__ ctrl, int NTOT) {
  constexpr int NT = KDIM / 32;  // K-tiles
  __shared__ __align__(16) char smem[32768];
  const int* rtp = ctrl + 25;

  // bijective XCD swizzle (m204): lin2 contiguous within an XCD's chunk
  const int nwg = gridDim.x * gridDim.y;
  const int lin = blockIdx.y * gridDim.x + blockIdx.x;
  const int xcd = lin & 7, loc = lin >> 3;
  const int q = nwg >> 3, rr = nwg & 7;
  const int lin2 = (xcd < rr ? xcd * (q + 1) : rr * (q + 1) + (xcd - rr) * q) + loc;
  // A-panel-major tile order (R6 lever)
  const int by = lin2 % gridDim.y;
  const int bx = lin2 / gridDim.y;
  if (bx >= rtp[EE]) return;
  int e = 0;
  while (bx >= rtp[e + 1]) ++e;
  const int rt = bx - rtp[e];
  const int row0 = ctrl[8 + e] + rt * 128;
  int vrows = ctrl[e] - rt * 128;
  if (vrows > 128) vrows = 128;
  const int n0 = by * 128;

  const int tid = threadIdx.x, lane = tid & 63, w = tid >> 6;
  const int wr = w >> 1, wc = w & 1;  // 2x2 waves; per-wave out 64x64

  // staging lane geometry (inverse swizzle on the global source)
  const int u = (lane * 16) ^ (((lane >> 5) & 1) << 5);
  const int ri = u >> 6;         // in-subtile row 0..15
  const int ci = (u & 63) >> 1;  // in-subtile col elem 0/8/16/24
  const unsigned short* pA = Amat + (size_t)(row0 + 32 * w + ri) * KDIM + ci;
  const unsigned short* pB = W + ((size_t)e * NTOT + n0 + 32 * w + ri) * KDIM + ci;
  char* sL = smem + (2 * w) * 1024 + lane * 16;

  // fragment-read lane term (swizzled): row=lane&15, col byte=(lane>>4)*16
  const int lt = (((lane & 15) << 6) | ((lane >> 4) << 4)) ^ (((lane >> 3) & 1) << 5);

  f32x4 acc[4][4];
#pragma unroll
  for (int m = 0; m < 4; ++m)
#pragma unroll
    for (int n = 0; n < 4; ++n) acc[m][n] = (f32x4){0.f, 0.f, 0.f, 0.f};

  bf16x8 a[4], b[4];

  // prologue
  STAGE(0, 0);
  __syncthreads();

  for (int kt = 0; kt < NT; ++kt) {
    const int p = kt & 1;
    if (kt + 1 < NT) STAGE(p ^ 1, kt + 1);
    const char* ab = smem + p * 16384 + wr * 4096 + lt;         // subtile wr*4+m
    const char* bb = smem + p * 16384 + 8192 + wc * 4096 + lt;  // subtile wc*4+n
#pragma unroll
    for (int m = 0; m < 4; ++m) a[m] = *(const bf16x8*)(ab + m * 1024);
#pragma unroll
    for (int n = 0; n < 4; ++n) b[n] = *(const bf16x8*)(bb + n * 1024);
#pragma unroll
    for (int m = 0; m < 4; ++m)
#pragma unroll
      for (int n = 0; n < 4; ++n)
        acc[m][n] = MF(a[m], b[n], acc[m][n]);
    __syncthreads();
  }

  // epilogue: wave piece rows wr*64+m*16, cols wc*64+n*16
#pragma unroll
  for (int m = 0; m < 4; ++m) {
    const int rbase = wr * 64 + m * 16 + (lane >> 4) * 4;
#pragma unroll
    for (int n = 0; n < 4; ++n) {
      const int col = n0 + wc * 64 + n * 16 + (lane & 15);
      const float bv_ = bias[(size_t)e * NTOT + col];
#pragma unroll
      for (int j = 0; j < 4; ++j) {
        const int r = rbase + j;
        if (r < vrows) {
          float vv = acc[m][n][j] + bv_;
          if constexpr (GELU) vv = 0.5f * vv * (1.0f + erff(vv * 0.70710678f));
          Outm[(size_t)(row0 + r) * NTOT + col] = f2bf(vv);
        }
      }
    }
  }
}

// -------------------- combine: out[t] = g0*Y[p0] + g1*Y[p1] --------------------
__global__ __launch_bounds__(256) void k_combine(
    const unsigned short* __restrict__ Y, const int* __restrict__ tok_pos,
    const float* __restrict__ gates, float* __restrict__ out) {
  int t = blockIdx.x, tid = threadIdx.x;
  int p0 = tok_pos[2 * t], p1 = tok_pos[2 * t + 1];
  float g0 = gates[2 * t], g1 = gates[2 * t + 1];
  ushort4 y0 = ((const ushort4*)(Y + (size_t)p0 * DD))[tid];
  ushort4 y1 = ((const ushort4*)(Y + (size_t)p1 * DD))[tid];
  float4 o;
  o.x = g0 * bf2f(y0.x) + g1 * bf2f(y1.x);
  o.y = g0 * bf2f(y0.y) + g1 * bf2f(y1.y);
  o.z = g0 * bf2f(y0.z) + g1 * bf2f(y1.z);
  o.w = g0 * bf2f(y0.w) + g1 * bf2f(y1.w);
  ((float4*)(out + (size_t)t * DD))[tid] = o;
}

__global__ __launch_bounds__(256) void k_sentinel(float* out, int n) {
  int i = blockIdx.x * 256 + threadIdx.x;
  if (i < n) out[i] = 12345.0f;
}

extern "C" void kernel_launch(void* const* d_in, const int* in_sizes, int n_in,
                              void* d_out, int out_size, void* d_ws, size_t ws_size,
                              hipStream_t stream) {
  const float* x   = (const float*)d_in[0];
  const float* rls = (const float*)d_in[1];
  const float* rlb = (const float*)d_in[2];
  const float* rw  = (const float*)d_in[3];
  const float* rb  = (const float*)d_in[4];
  const float* els = (const float*)d_in[5];
  const float* elb = (const float*)d_in[6];
  const float* w1  = (const float*)d_in[7];
  const float* b1  = (const float*)d_in[8];
  const float* w2  = (const float*)d_in[9];
  const float* b2  = (const float*)d_in[10];
  float* out = (float*)d_out;

  char* wsb = (char*)d_ws;
  size_t o = 0;
  int* ctrl = (int*)(wsb + o);                    o += 256;
  int* tok_pos = (int*)(wsb + o);                 o += (size_t)SLOTS * 4;
  float* gates = (float*)(wsb + o);               o += (size_t)SLOTS * 4;
  int* topk = (int*)(wsb + o);                    o += (size_t)TT * 4;
  int* ranks = (int*)(wsb + o);                   o += (size_t)SLOTS * 4;
  unsigned short* xhat = (unsigned short*)(wsb + o); o += (size_t)TT * DD * 2;
  unsigned short* Abuf = (unsigned short*)(wsb + o); o += (size_t)SLOTSP * DD * 2;
  unsigned short* w1b = (unsigned short*)(wsb + o);  o += (size_t)EE * HH * DD * 2;
  unsigned short* w2b = (unsigned short*)(wsb + o);  o += (size_t)EE * DD * HH * 2;
  unsigned short* Hm = (unsigned short*)(wsb + o);   o += (size_t)SLOTSP * HH * 2;
  unsigned short* Yb = (unsigned short*)(wsb + o);   o += (size_t)SLOTS * DD * 2;

  if (ws_size < o) {
    k_sentinel<<<(out_size + 255) / 256, 256, 0, stream>>>(out, out_size);
    return;
  }

  hipMemsetAsync(ctrl, 0, 256, stream);
  k_router<<<TT, 256, 0, stream>>>(x, rls, rlb, rw, rb, xhat, ctrl, topk, gates, ranks);
  k_wconv<<<65536, 256, 0, stream>>>(w1, w2, w1b, w2b);
  k_offsets<<<1, 64, 0, stream>>>(ctrl);
  k_build<<<SLOTS, 128, 0, stream>>>(xhat, els, elb, ctrl, topk, ranks, Abuf, tok_pos);
  k_gemm4<DD, true><<<dim3(MAXRT1, HH / 128), 256, 0, stream>>>(Abuf, w1b, b1, Hm, ctrl, HH);
  k_gemm4<HH, false><<<dim3(MAXRT1, DD / 128), 256, 0, stream>>>(Hm, w2b, b2, Yb, ctrl, DD);
  k_combine<<<TT, 256, 0, stream>>>(Yb, tok_pos, gates, out);
}